// Round 11
// baseline (76001.459 us; speedup 1.0000x reference)
//
#include <hip/hip_runtime.h>

#define EPSV 1e-5f

#define AT_LD(p)    __hip_atomic_load((p), __ATOMIC_RELAXED, __HIP_MEMORY_SCOPE_AGENT)
#define AT_ST(p, v) __hip_atomic_store((p), (v), __ATOMIC_RELAXED, __HIP_MEMORY_SCOPE_AGENT)

typedef unsigned int uint4v __attribute__((ext_vector_type(4)));

// ---------------- workspace layout (float offsets) ----------------
static constexpr long OFF_FDH   = 0;        // 8*512 ull fast tagged h data (XCD L2 lane)
static constexpr long OFF_FDR   = 8192;     // 8*512 ull fast tagged rh data
static constexpr long OFF_SDH   = 16384;    // 8*512 ull slow tagged h data (LLC lane)
static constexpr long OFF_SDR   = 24576;    // 8*512 ull slow tagged rh data
static constexpr long OFF_BAR   = 32768;    // 1 uint grid barrier
static constexpr long OFF_MEAN  = 33280;    // 512
static constexpr long OFF_SCALE = 33792;    // 512
static constexpr long OFF_OFFS  = 34304;    // 512
static constexpr long OFF_U0    = 40960;    // 8*38*512
static constexpr long OFF_U0N   = OFF_U0    + 155648;
static constexpr long OFF_R1    = OFF_U0N   + 155648;
static constexpr long OFF_U1    = OFF_R1    + 147456;
static constexpr long OFF_R2    = OFF_U1    + 147456;
static constexpr long OFF_U2    = OFF_R2    + 131072;
static constexpr long OFF_Y1    = OFF_U2    + 131072;
static constexpr long OFF_V1    = OFF_Y1    + 262144;
static constexpr long OFF_Y2    = OFF_V1    + 262144;
static constexpr long OFF_V2    = OFF_Y2    + 524288;
static constexpr long OFF_Y3    = OFF_V2    + 524288;
static constexpr long OFF_COND0 = OFF_Y3    + 2097152;
static constexpr long OFF_EWI   = OFF_COND0 + 2097152;
static constexpr long OFF_CGX   = OFF_EWI   + 393216;
static constexpr long OFF_HSEQ  = OFF_CGX   + 6291456;

__global__ void init_kernel(float* ws) {
    unsigned long long* fDH = (unsigned long long*)(ws + OFF_FDH);
    unsigned long long* fDR = (unsigned long long*)(ws + OFF_FDR);
    unsigned long long* sDH = (unsigned long long*)(ws + OFF_SDH);
    unsigned long long* sDR = (unsigned long long*)(ws + OFF_SDR);
    unsigned* bar = (unsigned*)(ws + OFF_BAR);
    int t = blockIdx.x * 256 + threadIdx.x;
    if (t < 4096) {
        AT_ST(&fDH[t], 0ull); AT_ST(&fDR[t], 0ull);
        AT_ST(&sDH[t], 0ull); AT_ST(&sDR[t], 0ull);
    }
    if (t == 0) AT_ST(bar, 0u);
}

// generic dilated valid conv1d, Cout = blockDim.x
__global__ void conv1d_kernel(const float* __restrict__ in, const float* __restrict__ w,
                              const float* __restrict__ b, float* __restrict__ out,
                              int T_in, int T_out, int Cin, int K, int rate) {
    extern __shared__ float s_in[];
    int n = blockIdx.x / T_out, t = blockIdx.x % T_out;
    int Cout = blockDim.x;
    for (int idx = threadIdx.x; idx < K * Cin; idx += Cout) {
        int k = idx / Cin, i = idx - k * Cin;
        s_in[idx] = in[((long)(n * T_in + t + k * rate)) * Cin + i];
    }
    __syncthreads();
    int c = threadIdx.x;
    float acc = b[c];
    for (int j = 0; j < K * Cin; ++j)
        acc += s_in[j] * w[(long)j * Cout + c];
    out[((long)(n * T_out + t)) * Cout + c] = acc;
}

// conv_transpose, kernel=1, SAME
__global__ void tconv1d_kernel(const float* __restrict__ in, const float* __restrict__ w,
                               const float* __restrict__ b, float* __restrict__ out,
                               int T_in, int stride, int Cin) {
    extern __shared__ float s_in[];
    int T_out = T_in * stride;
    int n = blockIdx.x / T_out, s = blockIdx.x % T_out;
    int Cout = blockDim.x;
    int c = threadIdx.x;
    if (s % stride) { out[((long)(n * T_out + s)) * Cout + c] = b[c]; return; }
    for (int i = threadIdx.x; i < Cin; i += Cout)
        s_in[i] = in[((long)(n * T_in + s / stride)) * Cin + i];
    __syncthreads();
    float acc = b[c];
    for (int i = 0; i < Cin; ++i) acc += s_in[i] * w[(long)i * Cout + c];
    out[((long)(n * T_out + s)) * Cout + c] = acc;
}

__global__ void bnstats_kernel(const float* __restrict__ x, const float* __restrict__ bns,
                               const float* __restrict__ bno, float* mean, float* scale,
                               float* offs, int count, int C) {
    int c = blockIdx.x, t = threadIdx.x;
    float s = 0.f, s2 = 0.f;
    for (int j = t; j < count; j += 64) { float v = x[(long)j * C + c]; s += v; s2 += v * v; }
    for (int off = 32; off; off >>= 1) { s += __shfl_down(s, off); s2 += __shfl_down(s2, off); }
    if (t == 0) {
        float m = s / count;
        float var = s2 / count - m * m;
        mean[c] = m;
        scale[c] = bns[c] * rsqrtf(var + EPSV);
        offs[c] = bno[c];
    }
}

__global__ void bnapply_kernel(const float* __restrict__ x, float* __restrict__ out,
                               const float* mean, const float* scale, const float* offs,
                               long total) {
    long i = (long)blockIdx.x * 256 + threadIdx.x;
    if (i >= total) return;
    int c = (int)(i & 511);
    float v = (x[i] - mean[c]) * scale[c] + offs[c];
    out[i] = fmaxf(v, 0.f);
}

__global__ void bnapply_add_kernel(const float* __restrict__ r, const float* __restrict__ base,
                                   float* __restrict__ out, const float* mean, const float* scale,
                                   const float* offs, int T_out, int T_base, int shift) {
    long i = (long)blockIdx.x * 256 + threadIdx.x;
    long total = (long)8 * T_out * 512;
    if (i >= total) return;
    int c = (int)(i & 511);
    long row = i >> 9;
    int n = (int)(row / T_out), t = (int)(row % T_out);
    float v = (r[i] - mean[c]) * scale[c] + offs[c];
    v = fmaxf(v, 0.f);
    out[i] = base[(((long)(n * T_base + t + shift)) << 9) + c] + v;
}

// out[rows x 1536] = A[rows x 512] @ W[512 x 1536]
__global__ void __launch_bounds__(256) rowgemm_kernel(const float* __restrict__ A,
                                                      const float* __restrict__ W,
                                                      float* __restrict__ out, int rows) {
    __shared__ float sA[16 * 512];
    long r0 = (long)blockIdx.x * 16;
    int t = threadIdx.x;
    for (int idx = t; idx < 16 * 512; idx += 256) sA[idx] = A[r0 * 512 + idx];
    __syncthreads();
    float acc[16][6];
#pragma unroll
    for (int r = 0; r < 16; ++r)
#pragma unroll
        for (int j = 0; j < 6; ++j) acc[r][j] = 0.f;
    for (int e = 0; e < 512; ++e) {
        float wv[6];
#pragma unroll
        for (int j = 0; j < 6; ++j) wv[j] = W[(long)e * 1536 + t + 256 * j];
#pragma unroll
        for (int r = 0; r < 16; ++r) {
            float a = sA[r * 512 + e];
#pragma unroll
            for (int j = 0; j < 6; ++j) acc[r][j] += a * wv[j];
        }
    }
    for (int r = 0; r < 16; ++r)
#pragma unroll
        for (int j = 0; j < 6; ++j) out[(r0 + r) * 1536 + t + 256 * j] = acc[r][j];
}

// ---------------- persistent GRU ----------------
// 256 wgs x 512 threads: batch n = blockIdx%8, role = blockIdx/8 owns 16 cols.
// Thread (col=t>>5, sub=t&31) owns h-elements {sub+32k}; 48 weights in VGPRs.
// Exchange: 8B tagged words (epoch<<32|f32), dual-published (plain -> local
// XCD L2; relaxed agent -> LLC). DETECTION: only WAVE 0 polls. Lane L owns 4
// aligned word-pairs {2L+128j}; each sweep = 4 independent dwordx4 sc0 loads
// in ONE asm block + single waitcnt -> full 512-word re-check every ~260cy,
// fully coalesced (4 cache lines/instr vs 512 scattered line-reqs of
// per-thread spinning -> no L2 poll storm). Arrivals written straight to LDS
// (single-leg). Own-WG words skipped (leads write LDS directly). Slow-LLC
// fallback every 8th sweep per remaining pair (liveness, no sticky demote).
#define GRU_LDS_BYTES 86016

__device__ __forceinline__ void pub_word(unsigned long long* fp, unsigned long long* sp,
                                         unsigned ep, float val) {
    unsigned long long w = ((unsigned long long)ep << 32) | (unsigned long long)__float_as_uint(val);
    *fp = w;        // plain store: local XCD L2
    AT_ST(sp, w);   // agent store: LLC (guaranteed lane)
}

// wave0 (lanes 0..63) sweep-polls 512 tagged words into lds; skip = pre-done pairs
__device__ __forceinline__ void wave0_poll(const unsigned long long* fbuf,
                                           const unsigned long long* sbuf,
                                           float* lds, unsigned ep, unsigned skip) {
    int L = threadIdx.x;   // < 64
    const unsigned long long* p0 = fbuf + 2 * L;
    const unsigned long long* p1 = fbuf + 2 * L + 128;
    const unsigned long long* p2 = fbuf + 2 * L + 256;
    const unsigned long long* p3 = fbuf + 2 * L + 384;
    unsigned todo = 0xFu & ~skip;
    int sweep = 0;
    while (todo) {
        uint4v q0, q1, q2, q3;
        asm volatile(
            "global_load_dwordx4 %0, %4, off sc0\n\t"
            "global_load_dwordx4 %1, %5, off sc0\n\t"
            "global_load_dwordx4 %2, %6, off sc0\n\t"
            "global_load_dwordx4 %3, %7, off sc0\n\t"
            "s_waitcnt vmcnt(0)"
            : "=&v"(q0), "=&v"(q1), "=&v"(q2), "=&v"(q3)
            : "v"(p0), "v"(p1), "v"(p2), "v"(p3)
            : "memory");
        if ((todo & 1u) && q0.y >= ep && q0.w >= ep) {
            lds[2 * L] = __uint_as_float(q0.x);
            lds[2 * L + 1] = __uint_as_float(q0.z);
            todo &= ~1u;
        }
        if ((todo & 2u) && q1.y >= ep && q1.w >= ep) {
            lds[2 * L + 128] = __uint_as_float(q1.x);
            lds[2 * L + 129] = __uint_as_float(q1.z);
            todo &= ~2u;
        }
        if ((todo & 4u) && q2.y >= ep && q2.w >= ep) {
            lds[2 * L + 256] = __uint_as_float(q2.x);
            lds[2 * L + 257] = __uint_as_float(q2.z);
            todo &= ~4u;
        }
        if ((todo & 8u) && q3.y >= ep && q3.w >= ep) {
            lds[2 * L + 384] = __uint_as_float(q3.x);
            lds[2 * L + 385] = __uint_as_float(q3.z);
            todo &= ~8u;
        }
        if (todo && ((++sweep & 7) == 0)) {   // slow-LLC fallback (rare)
#pragma unroll
            for (int j = 0; j < 4; ++j) {
                if (!(todo & (1u << j))) continue;
                int w = 2 * L + 128 * j;
                unsigned long long s0 = AT_LD(sbuf + w);
                unsigned long long s1 = AT_LD(sbuf + w + 1);
                if ((unsigned)(s0 >> 32) >= ep && (unsigned)(s1 >> 32) >= ep) {
                    lds[w] = __uint_as_float((unsigned)s0);
                    lds[w + 1] = __uint_as_float((unsigned)s1);
                    todo &= ~(1u << j);
                }
            }
        }
    }
}

__device__ __forceinline__ float red32(float a) {
    a += __shfl_down(a, 16, 32);
    a += __shfl_down(a, 8, 32);
    a += __shfl_down(a, 4, 32);
    a += __shfl_down(a, 2, 32);
    a += __shfl_down(a, 1, 32);
    return a;
}

__global__ void __launch_bounds__(512, 1) gru_kernel(
    const float* __restrict__ wh, const float* __restrict__ gb, const int* __restrict__ x,
    const float* __restrict__ ewi, const float* __restrict__ cgx, float* __restrict__ ws,
    float* __restrict__ hseq) {
    __shared__ float h_l[512];
    __shared__ float rh_l[512];
    extern __shared__ float lds_pad[];   // occupancy pad (1 WG/CU)
    (void)lds_pad;

    int wg = blockIdx.x;
    int n = wg & 7;
    int role = wg >> 3;
    int base = role * 16;
    int t = threadIdx.x;
    int col = t >> 5, sub = t & 31;
    int gcol = base + col;
    bool lead = (sub == 0);
    bool w0 = (t < 64);

    unsigned long long* fDHn = (unsigned long long*)(ws + OFF_FDH) + n * 512;
    unsigned long long* fDRn = (unsigned long long*)(ws + OFF_FDR) + n * 512;
    unsigned long long* sDHn = (unsigned long long*)(ws + OFF_SDH) + n * 512;
    unsigned long long* sDRn = (unsigned long long*)(ws + OFF_SDR) + n * 512;
    unsigned* bar = (unsigned*)(ws + OFF_BAR);

    // ---- per-thread weights into registers (one-time) ----
    float Wz[16], Wr[16], Wa[16];
#pragma unroll
    for (int k = 0; k < 16; ++k) {
        const float* row = wh + (long)(sub + 32 * k) * 1536;
        Wz[k] = row[gcol];
        Wr[k] = row[512 + gcol];
        Wa[k] = row[1024 + gcol];
    }
    float bzv = 0.f, brv = 0.f, bav = 0.f;
    if (lead) { bzv = gb[gcol]; brv = gb[512 + gcol]; bav = gb[1024 + gcol]; }

    // wave0: pre-skip mask for pairs covering OWN cols (leads write LDS directly)
    unsigned skip = 0;
    if (w0) {
#pragma unroll
        for (int j = 0; j < 4; ++j) {
            int w = 2 * t + 128 * j;
            if (w >= base && w < base + 16) skip |= (1u << j);
        }
    }

    // ---- sweep fast lane into OUR L2 (stale-proof across replays) ----
    fDHn[t] = 0ull;
    fDRn[t] = 0ull;
    h_l[t] = 0.f;
    asm volatile("s_waitcnt vmcnt(0)" ::: "memory");
    __syncthreads();
    // bounded grid barrier (liveness-safe)
    if (t == 0) {
        __hip_atomic_fetch_add(bar, 1u, __ATOMIC_RELAXED, __HIP_MEMORY_SCOPE_AGENT);
        for (int it = 0; it < 20000000; ++it) {
            if (AT_LD(bar) >= 256u) break;
            __builtin_amdgcn_s_sleep(2);
        }
    }
    __syncthreads();

    const float* cgxn = cgx + (long)n * 512 * 1536;
    float* hseqn = hseq + (long)n * 8192 * 512;
    float h_own = 0.f;                    // h[gcol], publisher-lane register

    // prefetch gate inputs for step 0
    float gz = 0.f, gr = 0.f, ga = 0.f;
    if (lead) {
        int xv = x[n * 8192];
        const float* e_row = ewi + (long)xv * 1536;
        gz = e_row[gcol] + cgxn[gcol] + bzv;
        gr = e_row[512 + gcol] + cgxn[512 + gcol] + brv;
        ga = e_row[1024 + gcol] + cgxn[1024 + gcol] + bav;
    }

    for (int l = 0; l < 8192; ++l) {
        unsigned ep1 = (unsigned)(l + 1);

        // ---- collect h_state(l): wave0 coalesced sweep-poll ----
        if (l > 0 && w0) wave0_poll(fDHn, sDHn, h_l, (unsigned)l, skip);
        __syncthreads();   // B1

        // ---- r matvec first: publish rh ASAP ----
        float accr = 0.f;
#pragma unroll
        for (int k = 0; k < 16; ++k) accr += h_l[sub + 32 * k] * Wr[k];
        accr = red32(accr);
        float rhv = 0.f;
        if (lead) {
            float rr = 1.f / (1.f + __expf(-(gr + accr)));
            rhv = rr * h_own;
            pub_word(&fDRn[gcol], &sDRn[gcol], ep1, rhv);
            rh_l[gcol] = rhv;              // own word local (skipped by poller)
        }

        // ---- z matvec: overlap under rh propagation ----
        float accz = 0.f;
#pragma unroll
        for (int k = 0; k < 16; ++k) accz += h_l[sub + 32 * k] * Wz[k];
        accz = red32(accz);
        float z = 0.f;
        if (lead) z = 1.f / (1.f + __expf(-(gz + accz)));

        // ---- collect rh(l): wave0 coalesced sweep-poll ----
        if (w0) wave0_poll(fDRn, sDRn, rh_l, ep1, skip);
        __syncthreads();   // B2

        // ---- a matvec + h update ----
        float acca = 0.f;
#pragma unroll
        for (int k = 0; k < 16; ++k) acca += rh_l[sub + 32 * k] * Wa[k];
        acca = red32(acca);
        if (lead) {
            float pre = ga + acca;
            float axv = fabsf(pre);
            float ex = __expf(-2.f * axv);
            float th = (1.f - ex) / (1.f + ex);
            float a = copysignf(th, pre);
            float hn = (1.f - z) * h_own + z * a;
            h_own = hn;
            if (l < 8191) pub_word(&fDHn[gcol], &sDHn[gcol], ep1, hn);
            h_l[gcol] = hn;                // own word local for next step
            hseqn[(long)l * 512 + gcol] = hn;
            // prefetch next step's gate inputs (hides under next h-wait)
            if (l < 8191) {
                int xv = x[n * 8192 + l + 1];
                const float* e_row = ewi + (long)xv * 1536;
                const float* c_row = cgxn + (long)((l + 1) >> 4) * 1536;
                gz = e_row[gcol] + c_row[gcol] + bzv;
                gr = e_row[512 + gcol] + c_row[512 + gcol] + brv;
                ga = e_row[1024 + gcol] + c_row[1024 + gcol] + bav;
            }
        }
    }
}

// fused head: relu(h@o1+b1)@o2+b2 -> log_softmax; 16 rows per block
__global__ void __launch_bounds__(256) head_kernel(const float* __restrict__ hseq,
                                                   const float* __restrict__ o1w,
                                                   const float* __restrict__ o1b,
                                                   const float* __restrict__ o2w,
                                                   const float* __restrict__ o2b,
                                                   float* __restrict__ out) {
    __shared__ float hs[16 * 512];
    long row0 = (long)blockIdx.x * 16;
    int t = threadIdx.x;
    for (int idx = t; idx < 16 * 512; idx += 256) hs[idx] = hseq[row0 * 512 + idx];
    __syncthreads();

    int c0 = t, c1 = t + 256;
    float acc[16][2];
#pragma unroll
    for (int r = 0; r < 16; ++r) { acc[r][0] = o1b[c0]; acc[r][1] = o1b[c1]; }
    for (int i = 0; i < 512; ++i) {
        float w0 = o1w[(long)i * 512 + c0], w1 = o1w[(long)i * 512 + c1];
#pragma unroll
        for (int r = 0; r < 16; ++r) {
            float h = hs[r * 512 + i];
            acc[r][0] += h * w0;
            acc[r][1] += h * w1;
        }
    }
    __syncthreads();
#pragma unroll
    for (int r = 0; r < 16; ++r) {
        hs[r * 512 + c0] = fmaxf(acc[r][0], 0.f);
        hs[r * 512 + c1] = fmaxf(acc[r][1], 0.f);
    }
    __syncthreads();

    float acc2[16];
#pragma unroll
    for (int r = 0; r < 16; ++r) acc2[r] = o2b[t];
    for (int i = 0; i < 512; ++i) {
        float w = o2w[(long)i * 256 + t];
#pragma unroll
        for (int r = 0; r < 16; ++r) acc2[r] += hs[r * 512 + i] * w;
    }
    __syncthreads();
#pragma unroll
    for (int r = 0; r < 16; ++r) hs[r * 256 + t] = acc2[r];
    __syncthreads();

    int wave = t >> 6, lane = t & 63;
    for (int rr = 0; rr < 4; ++rr) {
        int r = wave * 4 + rr;
        float v0 = hs[r * 256 + lane];
        float v1 = hs[r * 256 + 64 + lane];
        float v2 = hs[r * 256 + 128 + lane];
        float v3 = hs[r * 256 + 192 + lane];
        float m = fmaxf(fmaxf(v0, v1), fmaxf(v2, v3));
        for (int off = 32; off; off >>= 1) m = fmaxf(m, __shfl_xor(m, off));
        float s = __expf(v0 - m) + __expf(v1 - m) + __expf(v2 - m) + __expf(v3 - m);
        for (int off = 32; off; off >>= 1) s += __shfl_xor(s, off);
        float ls = m + logf(s);
        long ob = (row0 + r) * 256;
        out[ob + lane] = v0 - ls;
        out[ob + 64 + lane] = v1 - ls;
        out[ob + 128 + lane] = v2 - ls;
        out[ob + 192 + lane] = v3 - ls;
    }
}

extern "C" void kernel_launch(void* const* d_in, const int* in_sizes, int n_in,
                              void* d_out, int out_size, void* d_ws, size_t ws_size,
                              hipStream_t stream) {
    const int* x = (const int*)d_in[0];
    const float* mel = (const float*)d_in[1];
    const float* embed_w = (const float*)d_in[2];
    const float* conv_in_w = (const float*)d_in[3];
    const float* conv_in_b = (const float*)d_in[4];
    const float* conv_d1_w = (const float*)d_in[5];
    const float* conv_d1_b = (const float*)d_in[6];
    const float* conv_d2_w = (const float*)d_in[7];
    const float* conv_d2_b = (const float*)d_in[8];
    const float* up1_w = (const float*)d_in[9];
    const float* up1_b = (const float*)d_in[10];
    const float* up2_w = (const float*)d_in[11];
    const float* up2_b = (const float*)d_in[12];
    const float* up3_w = (const float*)d_in[13];
    const float* up3_b = (const float*)d_in[14];
    const float* bn_in_s = (const float*)d_in[15];
    const float* bn_in_o = (const float*)d_in[16];
    const float* bn_d1_s = (const float*)d_in[17];
    const float* bn_d1_o = (const float*)d_in[18];
    const float* bn_d2_s = (const float*)d_in[19];
    const float* bn_d2_o = (const float*)d_in[20];
    const float* bn_u1_s = (const float*)d_in[21];
    const float* bn_u1_o = (const float*)d_in[22];
    const float* bn_u2_s = (const float*)d_in[23];
    const float* bn_u2_o = (const float*)d_in[24];
    const float* bn_u3_s = (const float*)d_in[25];
    const float* bn_u3_o = (const float*)d_in[26];
    const float* gru_wi = (const float*)d_in[27];
    const float* gru_wh = (const float*)d_in[28];
    const float* gru_b = (const float*)d_in[29];
    const float* o1_w = (const float*)d_in[30];
    const float* o1_b = (const float*)d_in[31];
    const float* o2_w = (const float*)d_in[32];
    const float* o2_b = (const float*)d_in[33];

    float* ws = (float*)d_ws;
    float* out = (float*)d_out;

    float* mean = ws + OFF_MEAN;
    float* scale = ws + OFF_SCALE;
    float* offs = ws + OFF_OFFS;
    float* u0 = ws + OFF_U0;
    float* u0n = ws + OFF_U0N;
    float* r1 = ws + OFF_R1;
    float* u1 = ws + OFF_U1;
    float* r2 = ws + OFF_R2;
    float* u2 = ws + OFF_U2;
    float* y1 = ws + OFF_Y1;
    float* v1 = ws + OFF_V1;
    float* y2 = ws + OFF_Y2;
    float* v2 = ws + OFF_V2;
    float* y3 = ws + OFF_Y3;
    float* cond0 = ws + OFF_COND0;
    float* ewi = ws + OFF_EWI;
    float* cgx = ws + OFF_CGX;
    float* hseq = ws + OFF_HSEQ;

    init_kernel<<<16, 256, 0, stream>>>(ws);

    // conv_in (K3, rate1) + BN + relu
    conv1d_kernel<<<8 * 38, 512, 240 * 4, stream>>>(mel, conv_in_w, conv_in_b, u0, 40, 38, 80, 3, 1);
    bnstats_kernel<<<512, 64, 0, stream>>>(u0, bn_in_s, bn_in_o, mean, scale, offs, 304, 512);
    bnapply_kernel<<<155648 / 256, 256, 0, stream>>>(u0, u0n, mean, scale, offs, 155648);
    // dilated resblock 1
    conv1d_kernel<<<8 * 36, 512, 1024 * 4, stream>>>(u0n, conv_d1_w, conv_d1_b, r1, 38, 36, 512, 2, 2);
    bnstats_kernel<<<512, 64, 0, stream>>>(r1, bn_d1_s, bn_d1_o, mean, scale, offs, 288, 512);
    bnapply_add_kernel<<<147456 / 256, 256, 0, stream>>>(r1, u0n, u1, mean, scale, offs, 36, 38, 1);
    // dilated resblock 2
    conv1d_kernel<<<8 * 32, 512, 1024 * 4, stream>>>(u1, conv_d2_w, conv_d2_b, r2, 36, 32, 512, 2, 4);
    bnstats_kernel<<<512, 64, 0, stream>>>(r2, bn_d2_s, bn_d2_o, mean, scale, offs, 256, 512);
    bnapply_add_kernel<<<131072 / 256, 256, 0, stream>>>(r2, u1, u2, mean, scale, offs, 32, 36, 2);
    // upsample x2, x2, x4
    tconv1d_kernel<<<8 * 64, 512, 2048, stream>>>(u2, up1_w, up1_b, y1, 32, 2, 512);
    bnstats_kernel<<<512, 64, 0, stream>>>(y1, bn_u1_s, bn_u1_o, mean, scale, offs, 512, 512);
    bnapply_kernel<<<262144 / 256, 256, 0, stream>>>(y1, v1, mean, scale, offs, 262144);
    tconv1d_kernel<<<8 * 128, 512, 2048, stream>>>(v1, up2_w, up2_b, y2, 64, 2, 512);
    bnstats_kernel<<<512, 64, 0, stream>>>(y2, bn_u2_s, bn_u2_o, mean, scale, offs, 1024, 512);
    bnapply_kernel<<<524288 / 256, 256, 0, stream>>>(y2, v2, mean, scale, offs, 524288);
    tconv1d_kernel<<<8 * 512, 512, 2048, stream>>>(v2, up3_w, up3_b, y3, 128, 4, 512);
    bnstats_kernel<<<512, 64, 0, stream>>>(y3, bn_u3_s, bn_u3_o, mean, scale, offs, 4096, 512);
    bnapply_kernel<<<2097152 / 256, 256, 0, stream>>>(y3, cond0, mean, scale, offs, 2097152);

    // collapsed gx: ewi = embed@wi (256x1536), cgx = cond0@wi (4096x1536)
    rowgemm_kernel<<<16, 256, 0, stream>>>(embed_w, gru_wi, ewi, 256);
    rowgemm_kernel<<<256, 256, 0, stream>>>(cond0, gru_wi, cgx, 4096);

    // persistent GRU: 256 wgs x 512 threads; 84KB dynamic pad pins 1 WG/CU
    hipFuncSetAttribute(reinterpret_cast<const void*>(gru_kernel),
                        hipFuncAttributeMaxDynamicSharedMemorySize,
                        GRU_LDS_BYTES);
    gru_kernel<<<256, 512, GRU_LDS_BYTES, stream>>>(
        gru_wh, gru_b, x, ewi, cgx, ws, hseq);

    // fused output head + log_softmax
    head_kernel<<<4096, 256, 0, stream>>>(hseq, o1_w, o1_b, o2_w, o2_b, out);
}

// Round 12
// 20597.354 us; speedup vs baseline: 3.6899x; 3.6899x over previous
//
#include <hip/hip_runtime.h>

#define EPSV 1e-5f

#define AT_LD(p)    __hip_atomic_load((p), __ATOMIC_RELAXED, __HIP_MEMORY_SCOPE_AGENT)
#define AT_ST(p, v) __hip_atomic_store((p), (v), __ATOMIC_RELAXED, __HIP_MEMORY_SCOPE_AGENT)

// ---------------- workspace layout (float offsets) ----------------
static constexpr long OFF_SDH   = 0;        // 8*512 ull tagged h data (LLC lane)
static constexpr long OFF_SDR   = 8192;     // 8*512 ull tagged rh data (LLC lane)
static constexpr long OFF_MEAN  = 16896;    // 512
static constexpr long OFF_SCALE = 17408;    // 512
static constexpr long OFF_OFFS  = 17920;    // 512
static constexpr long OFF_U0    = 24576;    // 8*38*512
static constexpr long OFF_U0N   = OFF_U0    + 155648;
static constexpr long OFF_R1    = OFF_U0N   + 155648;
static constexpr long OFF_U1    = OFF_R1    + 147456;
static constexpr long OFF_R2    = OFF_U1    + 147456;
static constexpr long OFF_U2    = OFF_R2    + 131072;
static constexpr long OFF_Y1    = OFF_U2    + 131072;
static constexpr long OFF_V1    = OFF_Y1    + 262144;
static constexpr long OFF_Y2    = OFF_V1    + 262144;
static constexpr long OFF_V2    = OFF_Y2    + 524288;
static constexpr long OFF_Y3    = OFF_V2    + 524288;
static constexpr long OFF_COND0 = OFF_Y3    + 2097152;
static constexpr long OFF_EWI   = OFF_COND0 + 2097152;
static constexpr long OFF_CGX   = OFF_EWI   + 393216;
static constexpr long OFF_HSEQ  = OFF_CGX   + 6291456;

// zero the LLC tagged buffers (stream-ordered before gru_kernel; replay-safe:
// AT_LD/AT_ST bypass the incoherent per-XCD L2s, so no stale-line hazard).
__global__ void init_kernel(float* ws) {
    unsigned long long* sDH = (unsigned long long*)(ws + OFF_SDH);
    unsigned long long* sDR = (unsigned long long*)(ws + OFF_SDR);
    int t = blockIdx.x * 256 + threadIdx.x;
    if (t < 4096) { AT_ST(&sDH[t], 0ull); AT_ST(&sDR[t], 0ull); }
}

// generic dilated valid conv1d, Cout = blockDim.x
__global__ void conv1d_kernel(const float* __restrict__ in, const float* __restrict__ w,
                              const float* __restrict__ b, float* __restrict__ out,
                              int T_in, int T_out, int Cin, int K, int rate) {
    extern __shared__ float s_in[];
    int n = blockIdx.x / T_out, t = blockIdx.x % T_out;
    int Cout = blockDim.x;
    for (int idx = threadIdx.x; idx < K * Cin; idx += Cout) {
        int k = idx / Cin, i = idx - k * Cin;
        s_in[idx] = in[((long)(n * T_in + t + k * rate)) * Cin + i];
    }
    __syncthreads();
    int c = threadIdx.x;
    float acc = b[c];
    for (int j = 0; j < K * Cin; ++j)
        acc += s_in[j] * w[(long)j * Cout + c];
    out[((long)(n * T_out + t)) * Cout + c] = acc;
}

// conv_transpose, kernel=1, SAME
__global__ void tconv1d_kernel(const float* __restrict__ in, const float* __restrict__ w,
                               const float* __restrict__ b, float* __restrict__ out,
                               int T_in, int stride, int Cin) {
    extern __shared__ float s_in[];
    int T_out = T_in * stride;
    int n = blockIdx.x / T_out, s = blockIdx.x % T_out;
    int Cout = blockDim.x;
    int c = threadIdx.x;
    if (s % stride) { out[((long)(n * T_out + s)) * Cout + c] = b[c]; return; }
    for (int i = threadIdx.x; i < Cin; i += Cout)
        s_in[i] = in[((long)(n * T_in + s / stride)) * Cin + i];
    __syncthreads();
    float acc = b[c];
    for (int i = 0; i < Cin; ++i) acc += s_in[i] * w[(long)i * Cout + c];
    out[((long)(n * T_out + s)) * Cout + c] = acc;
}

__global__ void bnstats_kernel(const float* __restrict__ x, const float* __restrict__ bns,
                               const float* __restrict__ bno, float* mean, float* scale,
                               float* offs, int count, int C) {
    int c = blockIdx.x, t = threadIdx.x;
    float s = 0.f, s2 = 0.f;
    for (int j = t; j < count; j += 64) { float v = x[(long)j * C + c]; s += v; s2 += v * v; }
    for (int off = 32; off; off >>= 1) { s += __shfl_down(s, off); s2 += __shfl_down(s2, off); }
    if (t == 0) {
        float m = s / count;
        float var = s2 / count - m * m;
        mean[c] = m;
        scale[c] = bns[c] * rsqrtf(var + EPSV);
        offs[c] = bno[c];
    }
}

__global__ void bnapply_kernel(const float* __restrict__ x, float* __restrict__ out,
                               const float* mean, const float* scale, const float* offs,
                               long total) {
    long i = (long)blockIdx.x * 256 + threadIdx.x;
    if (i >= total) return;
    int c = (int)(i & 511);
    float v = (x[i] - mean[c]) * scale[c] + offs[c];
    out[i] = fmaxf(v, 0.f);
}

__global__ void bnapply_add_kernel(const float* __restrict__ r, const float* __restrict__ base,
                                   float* __restrict__ out, const float* mean, const float* scale,
                                   const float* offs, int T_out, int T_base, int shift) {
    long i = (long)blockIdx.x * 256 + threadIdx.x;
    long total = (long)8 * T_out * 512;
    if (i >= total) return;
    int c = (int)(i & 511);
    long row = i >> 9;
    int n = (int)(row / T_out), t = (int)(row % T_out);
    float v = (r[i] - mean[c]) * scale[c] + offs[c];
    v = fmaxf(v, 0.f);
    out[i] = base[(((long)(n * T_base + t + shift)) << 9) + c] + v;
}

// out[rows x 1536] = A[rows x 512] @ W[512 x 1536]
__global__ void __launch_bounds__(256) rowgemm_kernel(const float* __restrict__ A,
                                                      const float* __restrict__ W,
                                                      float* __restrict__ out, int rows) {
    __shared__ float sA[16 * 512];
    long r0 = (long)blockIdx.x * 16;
    int t = threadIdx.x;
    for (int idx = t; idx < 16 * 512; idx += 256) sA[idx] = A[r0 * 512 + idx];
    __syncthreads();
    float acc[16][6];
#pragma unroll
    for (int r = 0; r < 16; ++r)
#pragma unroll
        for (int j = 0; j < 6; ++j) acc[r][j] = 0.f;
    for (int e = 0; e < 512; ++e) {
        float wv[6];
#pragma unroll
        for (int j = 0; j < 6; ++j) wv[j] = W[(long)e * 1536 + t + 256 * j];
#pragma unroll
        for (int r = 0; r < 16; ++r) {
            float a = sA[r * 512 + e];
#pragma unroll
            for (int j = 0; j < 6; ++j) acc[r][j] += a * wv[j];
        }
    }
    for (int r = 0; r < 16; ++r)
#pragma unroll
        for (int j = 0; j < 6; ++j) out[(r0 + r) * 1536 + t + 256 * j] = acc[r][j];
}

// ---------------- persistent GRU ----------------
// 256 wgs x 512 threads: batch n = blockIdx%8, role = blockIdx/8 owns 16 cols.
// Thread (col=t>>5, sub=t&31) owns h-elements {sub+32k}; 48 weights in VGPRs.
// Exchange: PURE-LLC tagged 8B words (epoch<<32|f32). Publish = ONE relaxed
// agent store. Wait = per-thread TIGHT dependent-load spin on its own word
// (no fast probes — R6..R11 established the cross-WG XCD-L2 lane never hits;
// per-XCD L2s aren't coherent). Own-WG words skipped (leads write LDS
// directly). 2 barriers/step. Balanced 64B lead hseq writes.
#define GRU_LDS_BYTES 86016

__device__ __forceinline__ void pub_word(unsigned long long* sp, unsigned ep, float val) {
    unsigned long long w = ((unsigned long long)ep << 32) | (unsigned long long)__float_as_uint(val);
    AT_ST(sp, w);
}

__device__ __forceinline__ float wait_word(const unsigned long long* sp, unsigned ep) {
    unsigned long long v = AT_LD(sp);
    while ((unsigned)(v >> 32) < ep) v = AT_LD(sp);   // tight: period = LLC latency
    return __uint_as_float((unsigned)(v & 0xFFFFFFFFull));
}

__device__ __forceinline__ float red32(float a) {
    a += __shfl_down(a, 16, 32);
    a += __shfl_down(a, 8, 32);
    a += __shfl_down(a, 4, 32);
    a += __shfl_down(a, 2, 32);
    a += __shfl_down(a, 1, 32);
    return a;
}

__global__ void __launch_bounds__(512, 1) gru_kernel(
    const float* __restrict__ wh, const float* __restrict__ gb, const int* __restrict__ x,
    const float* __restrict__ ewi, const float* __restrict__ cgx,
    unsigned long long* __restrict__ sDH, unsigned long long* __restrict__ sDR,
    float* __restrict__ hseq) {
    __shared__ float h_l[512];
    __shared__ float rh_l[512];
    extern __shared__ float lds_pad[];   // occupancy pad (1 WG/CU)
    (void)lds_pad;

    int wg = blockIdx.x;
    int n = wg & 7;
    int role = wg >> 3;
    int base = role * 16;
    int t = threadIdx.x;
    int col = t >> 5, sub = t & 31;
    int gcol = base + col;
    bool lead = (sub == 0);
    bool own = ((t >> 4) == role);       // this thread's exchange word is own-WG

    unsigned long long* sDHn = sDH + n * 512;
    unsigned long long* sDRn = sDR + n * 512;

    // ---- per-thread weights into registers (one-time) ----
    float Wz[16], Wr[16], Wa[16];
#pragma unroll
    for (int k = 0; k < 16; ++k) {
        const float* row = wh + (long)(sub + 32 * k) * 1536;
        Wz[k] = row[gcol];
        Wr[k] = row[512 + gcol];
        Wa[k] = row[1024 + gcol];
    }
    float bzv = 0.f, brv = 0.f, bav = 0.f;
    if (lead) { bzv = gb[gcol]; brv = gb[512 + gcol]; bav = gb[1024 + gcol]; }

    h_l[t] = 0.f;
    __syncthreads();

    const float* cgxn = cgx + (long)n * 512 * 1536;
    float* hseqn = hseq + (long)n * 8192 * 512;
    float h_own = 0.f;                    // h[gcol], publisher-lane register

    // prefetch gate inputs for step 0
    float gz = 0.f, gr = 0.f, ga = 0.f;
    if (lead) {
        int xv = x[n * 8192];
        const float* e_row = ewi + (long)xv * 1536;
        gz = e_row[gcol] + cgxn[gcol] + bzv;
        gr = e_row[512 + gcol] + cgxn[512 + gcol] + brv;
        ga = e_row[1024 + gcol] + cgxn[1024 + gcol] + bav;
    }

    for (int l = 0; l < 8192; ++l) {
        unsigned ep1 = (unsigned)(l + 1);

        // ---- collect h_state(l): spin on OWN word (own-WG cols already in LDS) ----
        if (l > 0 && !own) h_l[t] = wait_word(&sDHn[t], (unsigned)l);
        __syncthreads();   // B1

        // ---- r matvec first: publish rh ASAP (cross-WG critical path) ----
        float accr = 0.f;
#pragma unroll
        for (int k = 0; k < 16; ++k) accr += h_l[sub + 32 * k] * Wr[k];
        accr = red32(accr);
        if (lead) {
            float rr = 1.f / (1.f + __expf(-(gr + accr)));
            float rhv = rr * h_own;
            pub_word(&sDRn[gcol], ep1, rhv);
            rh_l[gcol] = rhv;              // own cols local (no self-poll)
        }

        // ---- z matvec: overlaps rh propagation ----
        float accz = 0.f;
#pragma unroll
        for (int k = 0; k < 16; ++k) accz += h_l[sub + 32 * k] * Wz[k];
        accz = red32(accz);
        float z = 0.f;
        if (lead) z = 1.f / (1.f + __expf(-(gz + accz)));

        // ---- collect rh(l) ----
        if (!own) rh_l[t] = wait_word(&sDRn[t], ep1);
        __syncthreads();   // B2

        // ---- a matvec + h update ----
        float acca = 0.f;
#pragma unroll
        for (int k = 0; k < 16; ++k) acca += rh_l[sub + 32 * k] * Wa[k];
        acca = red32(acca);
        if (lead) {
            float pre = ga + acca;
            float axv = fabsf(pre);
            float ex = __expf(-2.f * axv);
            float th = (1.f - ex) / (1.f + ex);
            float a = copysignf(th, pre);
            float hn = (1.f - z) * h_own + z * a;
            h_own = hn;
            if (l < 8191) pub_word(&sDHn[gcol], ep1, hn);
            h_l[gcol] = hn;                // own cols local for next step
            hseqn[(long)l * 512 + gcol] = hn;   // balanced 64B contiguous per WG
            // prefetch next step's gate inputs (hides under next h-wait)
            if (l < 8191) {
                int xv = x[n * 8192 + l + 1];
                const float* e_row = ewi + (long)xv * 1536;
                const float* c_row = cgxn + (long)((l + 1) >> 4) * 1536;
                gz = e_row[gcol] + c_row[gcol] + bzv;
                gr = e_row[512 + gcol] + c_row[512 + gcol] + brv;
                ga = e_row[1024 + gcol] + c_row[1024 + gcol] + bav;
            }
        }
    }
}

// fused head: relu(h@o1+b1)@o2+b2 -> log_softmax; 16 rows per block
__global__ void __launch_bounds__(256) head_kernel(const float* __restrict__ hseq,
                                                   const float* __restrict__ o1w,
                                                   const float* __restrict__ o1b,
                                                   const float* __restrict__ o2w,
                                                   const float* __restrict__ o2b,
                                                   float* __restrict__ out) {
    __shared__ float hs[16 * 512];
    long row0 = (long)blockIdx.x * 16;
    int t = threadIdx.x;
    for (int idx = t; idx < 16 * 512; idx += 256) hs[idx] = hseq[row0 * 512 + idx];
    __syncthreads();

    int c0 = t, c1 = t + 256;
    float acc[16][2];
#pragma unroll
    for (int r = 0; r < 16; ++r) { acc[r][0] = o1b[c0]; acc[r][1] = o1b[c1]; }
    for (int i = 0; i < 512; ++i) {
        float w0 = o1w[(long)i * 512 + c0], w1 = o1w[(long)i * 512 + c1];
#pragma unroll
        for (int r = 0; r < 16; ++r) {
            float h = hs[r * 512 + i];
            acc[r][0] += h * w0;
            acc[r][1] += h * w1;
        }
    }
    __syncthreads();
#pragma unroll
    for (int r = 0; r < 16; ++r) {
        hs[r * 512 + c0] = fmaxf(acc[r][0], 0.f);
        hs[r * 512 + c1] = fmaxf(acc[r][1], 0.f);
    }
    __syncthreads();

    float acc2[16];
#pragma unroll
    for (int r = 0; r < 16; ++r) acc2[r] = o2b[t];
    for (int i = 0; i < 512; ++i) {
        float w = o2w[(long)i * 256 + t];
#pragma unroll
        for (int r = 0; r < 16; ++r) acc2[r] += hs[r * 512 + i] * w;
    }
    __syncthreads();
#pragma unroll
    for (int r = 0; r < 16; ++r) hs[r * 256 + t] = acc2[r];
    __syncthreads();

    int wave = t >> 6, lane = t & 63;
    for (int rr = 0; rr < 4; ++rr) {
        int r = wave * 4 + rr;
        float v0 = hs[r * 256 + lane];
        float v1 = hs[r * 256 + 64 + lane];
        float v2 = hs[r * 256 + 128 + lane];
        float v3 = hs[r * 256 + 192 + lane];
        float m = fmaxf(fmaxf(v0, v1), fmaxf(v2, v3));
        for (int off = 32; off; off >>= 1) m = fmaxf(m, __shfl_xor(m, off));
        float s = __expf(v0 - m) + __expf(v1 - m) + __expf(v2 - m) + __expf(v3 - m);
        for (int off = 32; off; off >>= 1) s += __shfl_xor(s, off);
        float ls = m + logf(s);
        long ob = (row0 + r) * 256;
        out[ob + lane] = v0 - ls;
        out[ob + 64 + lane] = v1 - ls;
        out[ob + 128 + lane] = v2 - ls;
        out[ob + 192 + lane] = v3 - ls;
    }
}

extern "C" void kernel_launch(void* const* d_in, const int* in_sizes, int n_in,
                              void* d_out, int out_size, void* d_ws, size_t ws_size,
                              hipStream_t stream) {
    const int* x = (const int*)d_in[0];
    const float* mel = (const float*)d_in[1];
    const float* embed_w = (const float*)d_in[2];
    const float* conv_in_w = (const float*)d_in[3];
    const float* conv_in_b = (const float*)d_in[4];
    const float* conv_d1_w = (const float*)d_in[5];
    const float* conv_d1_b = (const float*)d_in[6];
    const float* conv_d2_w = (const float*)d_in[7];
    const float* conv_d2_b = (const float*)d_in[8];
    const float* up1_w = (const float*)d_in[9];
    const float* up1_b = (const float*)d_in[10];
    const float* up2_w = (const float*)d_in[11];
    const float* up2_b = (const float*)d_in[12];
    const float* up3_w = (const float*)d_in[13];
    const float* up3_b = (const float*)d_in[14];
    const float* bn_in_s = (const float*)d_in[15];
    const float* bn_in_o = (const float*)d_in[16];
    const float* bn_d1_s = (const float*)d_in[17];
    const float* bn_d1_o = (const float*)d_in[18];
    const float* bn_d2_s = (const float*)d_in[19];
    const float* bn_d2_o = (const float*)d_in[20];
    const float* bn_u1_s = (const float*)d_in[21];
    const float* bn_u1_o = (const float*)d_in[22];
    const float* bn_u2_s = (const float*)d_in[23];
    const float* bn_u2_o = (const float*)d_in[24];
    const float* bn_u3_s = (const float*)d_in[25];
    const float* bn_u3_o = (const float*)d_in[26];
    const float* gru_wi = (const float*)d_in[27];
    const float* gru_wh = (const float*)d_in[28];
    const float* gru_b = (const float*)d_in[29];
    const float* o1_w = (const float*)d_in[30];
    const float* o1_b = (const float*)d_in[31];
    const float* o2_w = (const float*)d_in[32];
    const float* o2_b = (const float*)d_in[33];

    float* ws = (float*)d_ws;
    float* out = (float*)d_out;

    unsigned long long* sDH = (unsigned long long*)(ws + OFF_SDH);
    unsigned long long* sDR = (unsigned long long*)(ws + OFF_SDR);
    float* mean = ws + OFF_MEAN;
    float* scale = ws + OFF_SCALE;
    float* offs = ws + OFF_OFFS;
    float* u0 = ws + OFF_U0;
    float* u0n = ws + OFF_U0N;
    float* r1 = ws + OFF_R1;
    float* u1 = ws + OFF_U1;
    float* r2 = ws + OFF_R2;
    float* u2 = ws + OFF_U2;
    float* y1 = ws + OFF_Y1;
    float* v1 = ws + OFF_V1;
    float* y2 = ws + OFF_Y2;
    float* v2 = ws + OFF_V2;
    float* y3 = ws + OFF_Y3;
    float* cond0 = ws + OFF_COND0;
    float* ewi = ws + OFF_EWI;
    float* cgx = ws + OFF_CGX;
    float* hseq = ws + OFF_HSEQ;

    init_kernel<<<16, 256, 0, stream>>>(ws);

    // conv_in (K3, rate1) + BN + relu
    conv1d_kernel<<<8 * 38, 512, 240 * 4, stream>>>(mel, conv_in_w, conv_in_b, u0, 40, 38, 80, 3, 1);
    bnstats_kernel<<<512, 64, 0, stream>>>(u0, bn_in_s, bn_in_o, mean, scale, offs, 304, 512);
    bnapply_kernel<<<155648 / 256, 256, 0, stream>>>(u0, u0n, mean, scale, offs, 155648);
    // dilated resblock 1
    conv1d_kernel<<<8 * 36, 512, 1024 * 4, stream>>>(u0n, conv_d1_w, conv_d1_b, r1, 38, 36, 512, 2, 2);
    bnstats_kernel<<<512, 64, 0, stream>>>(r1, bn_d1_s, bn_d1_o, mean, scale, offs, 288, 512);
    bnapply_add_kernel<<<147456 / 256, 256, 0, stream>>>(r1, u0n, u1, mean, scale, offs, 36, 38, 1);
    // dilated resblock 2
    conv1d_kernel<<<8 * 32, 512, 1024 * 4, stream>>>(u1, conv_d2_w, conv_d2_b, r2, 36, 32, 512, 2, 4);
    bnstats_kernel<<<512, 64, 0, stream>>>(r2, bn_d2_s, bn_d2_o, mean, scale, offs, 256, 512);
    bnapply_add_kernel<<<131072 / 256, 256, 0, stream>>>(r2, u1, u2, mean, scale, offs, 32, 36, 2);
    // upsample x2, x2, x4
    tconv1d_kernel<<<8 * 64, 512, 2048, stream>>>(u2, up1_w, up1_b, y1, 32, 2, 512);
    bnstats_kernel<<<512, 64, 0, stream>>>(y1, bn_u1_s, bn_u1_o, mean, scale, offs, 512, 512);
    bnapply_kernel<<<262144 / 256, 256, 0, stream>>>(y1, v1, mean, scale, offs, 262144);
    tconv1d_kernel<<<8 * 128, 512, 2048, stream>>>(v1, up2_w, up2_b, y2, 64, 2, 512);
    bnstats_kernel<<<512, 64, 0, stream>>>(y2, bn_u2_s, bn_u2_o, mean, scale, offs, 1024, 512);
    bnapply_kernel<<<524288 / 256, 256, 0, stream>>>(y2, v2, mean, scale, offs, 524288);
    tconv1d_kernel<<<8 * 512, 512, 2048, stream>>>(v2, up3_w, up3_b, y3, 128, 4, 512);
    bnstats_kernel<<<512, 64, 0, stream>>>(y3, bn_u3_s, bn_u3_o, mean, scale, offs, 4096, 512);
    bnapply_kernel<<<2097152 / 256, 256, 0, stream>>>(y3, cond0, mean, scale, offs, 2097152);

    // collapsed gx: ewi = embed@wi (256x1536), cgx = cond0@wi (4096x1536)
    rowgemm_kernel<<<16, 256, 0, stream>>>(embed_w, gru_wi, ewi, 256);
    rowgemm_kernel<<<256, 256, 0, stream>>>(cond0, gru_wi, cgx, 4096);

    // persistent GRU: 256 wgs x 512 threads; 84KB dynamic pad pins 1 WG/CU
    hipFuncSetAttribute(reinterpret_cast<const void*>(gru_kernel),
                        hipFuncAttributeMaxDynamicSharedMemorySize,
                        GRU_LDS_BYTES);
    gru_kernel<<<256, 512, GRU_LDS_BYTES, stream>>>(
        gru_wh, gru_b, x, ewi, cgx, sDH, sDR, hseq);

    // fused output head + log_softmax
    head_kernel<<<4096, 256, 0, stream>>>(hseq, o1_w, o1_b, o2_w, o2_b, out);
}